// Round 5
// baseline (596.994 us; speedup 1.0000x reference)
//
#include <hip/hip_runtime.h>
#include <hip/hip_bf16.h>
#include <stdint.h>

#define B_    8
#define S_    4096
#define DIN   2048
#define DOUT  2048
#define P_    256
#define M_    (B_ * S_)   // 32768

typedef __attribute__((ext_vector_type(4))) float f32x4;
typedef __attribute__((ext_vector_type(8))) short bf16x8;
typedef __attribute__((ext_vector_type(4))) short bf16x4;

static __device__ __forceinline__ short f2bs(float x) {
    __hip_bfloat16 h = __float2bfloat16(x);
    return *reinterpret_cast<short*>(&h);
}

// global -> LDS async DMA, 16 B per lane (wave writes lds_base + lane*16)
static __device__ __forceinline__ void gld_lds16(const void* g, void* l) {
    __builtin_amdgcn_global_load_lds(
        (const __attribute__((address_space(1))) unsigned int*)(uintptr_t)g,
        (__attribute__((address_space(3))) unsigned int*)(uintptr_t)l,
        16, 0, 0);
}

// XOR swizzle for 64x64 bf16 tiles (row stride 128 B): balanced 8-per-bank-group
#define SWZ(row, byteoff) ((byteoff) ^ (((row) & 7) << 4))

// ---------------------------------------------------------------------------
// Prep 1: left [P][DIN] fp32 -> bf16 flat (linear; consumed by register loads)
// ---------------------------------------------------------------------------
__global__ __launch_bounds__(256)
void cvt_left(const float* __restrict__ src, short* __restrict__ dst) {
    int i = blockIdx.x * 256 + threadIdx.x;       // (P_*DIN)/8 = 65536 chunks
    const float4* s = reinterpret_cast<const float4*>(src) + (size_t)i * 2;
    float4 a = s[0], b = s[1];
    bf16x8 o;
    o[0]=f2bs(a.x); o[1]=f2bs(a.y); o[2]=f2bs(a.z); o[3]=f2bs(a.w);
    o[4]=f2bs(b.x); o[5]=f2bs(b.y); o[6]=f2bs(b.z); o[7]=f2bs(b.w);
    *(reinterpret_cast<bf16x8*>(dst) + i) = o;
}

// ---------------------------------------------------------------------------
// Prep 2: Rt[n][p] = bf16(right[p][n])  (linear transposed bf16)
// ---------------------------------------------------------------------------
__global__ __launch_bounds__(256)
void transposeR(const float* __restrict__ R, short* __restrict__ Rt) {
    __shared__ float T[64][65];
    const int n0 = blockIdx.x * 64;   // DOUT dim
    const int p0 = blockIdx.y * 64;   // P dim
    const int tid = threadIdx.x;
    #pragma unroll
    for (int e = 0; e < 16; ++e) {
        int idx = tid + e * 256;
        int r = idx >> 6, c = idx & 63;
        T[r][c] = R[(size_t)(p0 + r) * DOUT + n0 + c];
    }
    __syncthreads();
    #pragma unroll
    for (int e = 0; e < 4; ++e) {
        int g = tid + e * 256;
        int n = g >> 4, p4 = (g & 15) << 2;
        bf16x4 v;
        v[0] = f2bs(T[p4 + 0][n]); v[1] = f2bs(T[p4 + 1][n]);
        v[2] = f2bs(T[p4 + 2][n]); v[3] = f2bs(T[p4 + 3][n]);
        *reinterpret_cast<bf16x4*>(&Rt[(size_t)(n0 + n) * P_ + p0 + p4]) = v;
    }
}

// ---------------------------------------------------------------------------
// Prep 3: mb[b,k] = meta[b,:] @ bias_w[:,k] + bias_b[k].  64 blocks.
// ---------------------------------------------------------------------------
__global__ __launch_bounds__(256)
void meta_bias(const float* __restrict__ meta,
               const float* __restrict__ bias_w,
               const float* __restrict__ bias_b,
               float* __restrict__ mb) {
    int b = blockIdx.x >> 3;
    int k = (blockIdx.x & 7) * 256 + threadIdx.x;
    const float* mrow = meta + b * P_;              // b uniform -> scalar loads
    float acc = bias_b[k];
    #pragma unroll 8
    for (int p = 0; p < P_; ++p)
        acc = fmaf(mrow[p], bias_w[(size_t)p * DOUT + k], acc);
    mb[(size_t)b * DOUT + k] = acc;
}

// ---------------------------------------------------------------------------
// Stage 1: Hsw = swizzled-bf16-images( (X @ left^T) * meta )
// BM=64 x BN=256 (full P), BK=64, 4 waves (wave w -> cols w*64..w*64+63).
// A (X fp32): reg-load kt+1 early (T14), cvt, ds_write to double-buffered As.
// B (left bf16): DIRECT register loads from L2 (no reuse inside block -> no LDS).
// One barrier per k-tile.  LDS = 16 KB.  Grid 512 = 2 blocks/CU.
// ---------------------------------------------------------------------------
__global__ __launch_bounds__(256, 2)
void gemm1(const float* __restrict__ X, const short* __restrict__ Lb,
           const float* __restrict__ meta, char* __restrict__ Hsw) {
    __shared__ short As[2][64 * 64];   // 2 x 8 KB

    const int tid  = threadIdx.x;
    const int lane = tid & 63;
    const int w    = tid >> 6;
    const int lm   = lane & 15;
    const int rg   = lane >> 4;
    const int mblk = blockIdx.x;       // 0..511
    const int r0   = mblk * 64;
    const int bidx = mblk >> 6;

    // staging geometry: each thread owns 64 contiguous bytes of one X row
    const int row_s = tid >> 2;        // 0..63
    const int kq    = (tid & 3) * 16;  // float offset within 64-float k-tile
    const float* xbase = X + (size_t)(r0 + row_s) * DIN + kq;
    const int wsw0 = SWZ(row_s, row_s * 128 + kq * 2);
    const int wsw1 = SWZ(row_s, row_s * 128 + kq * 2 + 16);

    f32x4 acc[4][4] = {};
    float4 xr0, xr1, xr2, xr3;
    {
        const float4* s = reinterpret_cast<const float4*>(xbase);
        xr0 = s[0]; xr1 = s[1]; xr2 = s[2]; xr3 = s[3];
    }

    for (int kt = 0; kt < 32; ++kt) {
        char* asb = (char*)As[kt & 1];
        // cvt staged regs -> LDS (balanced-8 banks, no extra conflict)
        bf16x8 o0, o1;
        o0[0]=f2bs(xr0.x); o0[1]=f2bs(xr0.y); o0[2]=f2bs(xr0.z); o0[3]=f2bs(xr0.w);
        o0[4]=f2bs(xr1.x); o0[5]=f2bs(xr1.y); o0[6]=f2bs(xr1.z); o0[7]=f2bs(xr1.w);
        o1[0]=f2bs(xr2.x); o1[1]=f2bs(xr2.y); o1[2]=f2bs(xr2.z); o1[3]=f2bs(xr2.w);
        o1[4]=f2bs(xr3.x); o1[5]=f2bs(xr3.y); o1[6]=f2bs(xr3.z); o1[7]=f2bs(xr3.w);
        *reinterpret_cast<bf16x8*>(asb + wsw0) = o0;
        *reinterpret_cast<bf16x8*>(asb + wsw1) = o1;
        __syncthreads();                       // As[kt&1] ready (dbuf: 1 barrier/iter)

        // issue next k-tile's X loads NOW; consumed next iteration (T14)
        if (kt < 31) {
            const float4* s = reinterpret_cast<const float4*>(xbase + (kt + 1) * 64);
            xr0 = s[0]; xr1 = s[1]; xr2 = s[2]; xr3 = s[3];
        }

        // B fragments direct from L2-resident bf16 left
        bf16x8 bfr[4][2];
        #pragma unroll
        for (int j = 0; j < 4; ++j)
            #pragma unroll
            for (int kk = 0; kk < 2; ++kk)
                bfr[j][kk] = *reinterpret_cast<const bf16x8*>(
                    Lb + (size_t)(w * 64 + j * 16 + lm) * DIN + kt * 64 + kk * 32 + rg * 8);

        #pragma unroll
        for (int kk = 0; kk < 2; ++kk) {
            bf16x8 af[4];
            #pragma unroll
            for (int i = 0; i < 4; ++i) {
                int m = i * 16 + lm;
                af[i] = *reinterpret_cast<const bf16x8*>(
                    asb + SWZ(m, m * 128 + (kk * 32 + rg * 8) * 2));
            }
            #pragma unroll
            for (int i = 0; i < 4; ++i)
                #pragma unroll
                for (int j = 0; j < 4; ++j)
                    acc[i][j] = __builtin_amdgcn_mfma_f32_16x16x32_bf16(
                        af[i], bfr[j][kk], acc[i][j], 0, 0, 0);
        }
        // no trailing barrier: double buffer
    }

    // epilogue: *meta, write swizzled H image (wave w == k-tile image w)
    const float* mrow = meta + bidx * P_;
    char* hb = Hsw + (size_t)mblk * 32768 + w * 8192;
    float mv[4];
    #pragma unroll
    for (int j = 0; j < 4; ++j) mv[j] = mrow[w * 64 + j * 16 + lm];
    #pragma unroll
    for (int i = 0; i < 4; ++i) {
        #pragma unroll
        for (int j = 0; j < 4; ++j) {
            int kk2 = j * 16 + lm;                 // 0..63 within image
            #pragma unroll
            for (int q = 0; q < 4; ++q) {
                int r = i * 16 + rg * 4 + q;       // 0..63
                *reinterpret_cast<short*>(hb + SWZ(r, r * 128 + kk2 * 2)) =
                    f2bs(acc[i][j][q] * mv[j]);
            }
        }
    }
}

// ---------------------------------------------------------------------------
// Stage 2: out = H @ right + mb
// BM=64 x BN=256, K=256 (4 k-tiles). A: H images via gld_lds (8 KB).
// B: DIRECT register loads from L2-resident Rt.  Grid (512,8) -> 3 blocks/CU.
// ---------------------------------------------------------------------------
__global__ __launch_bounds__(256, 3)
void gemm2(const char* __restrict__ Hsw, const short* __restrict__ Rt,
           const float* __restrict__ mb, float* __restrict__ O) {
    __shared__ short As[64 * 64];      // 8 KB

    const int tid  = threadIdx.x;
    const int lane = tid & 63;
    const int w    = tid >> 6;
    const int lm   = lane & 15;
    const int rg   = lane >> 4;
    const int mblk = blockIdx.x;       // 0..511
    const int r0   = mblk * 64;
    const int c0   = blockIdx.y * 256;
    const int bidx = mblk >> 6;
    char* asb = (char*)As;

    f32x4 acc[4][4] = {};

    for (int kt = 0; kt < 4; ++kt) {
        const char* aimg = Hsw + ((size_t)mblk * 4 + kt) * 8192;
        gld_lds16(aimg + (w * 2 + 0) * 1024 + lane * 16, asb + (w * 2 + 0) * 1024);
        gld_lds16(aimg + (w * 2 + 1) * 1024 + lane * 16, asb + (w * 2 + 1) * 1024);
        __syncthreads();               // vmcnt(0) drain: A tile in LDS

        bf16x8 bfr[4][2];
        #pragma unroll
        for (int j = 0; j < 4; ++j)
            #pragma unroll
            for (int kk = 0; kk < 2; ++kk)
                bfr[j][kk] = *reinterpret_cast<const bf16x8*>(
                    Rt + (size_t)(c0 + w * 64 + j * 16 + lm) * P_ + kt * 64 + kk * 32 + rg * 8);

        #pragma unroll
        for (int kk = 0; kk < 2; ++kk) {
            bf16x8 af[4];
            #pragma unroll
            for (int i = 0; i < 4; ++i) {
                int m = i * 16 + lm;
                af[i] = *reinterpret_cast<const bf16x8*>(
                    asb + SWZ(m, m * 128 + (kk * 32 + rg * 8) * 2));
            }
            #pragma unroll
            for (int i = 0; i < 4; ++i)
                #pragma unroll
                for (int j = 0; j < 4; ++j)
                    acc[i][j] = __builtin_amdgcn_mfma_f32_16x16x32_bf16(
                        af[i], bfr[j][kk], acc[i][j], 0, 0, 0);
        }
        __syncthreads();               // protect As before next gld_lds
    }

    const float* mbr = mb + (size_t)bidx * DOUT;
    float bv[4];
    #pragma unroll
    for (int j = 0; j < 4; ++j) bv[j] = mbr[c0 + w * 64 + j * 16 + lm];
    #pragma unroll
    for (int i = 0; i < 4; ++i) {
        #pragma unroll
        for (int j = 0; j < 4; ++j) {
            int col = c0 + w * 64 + j * 16 + lm;
            #pragma unroll
            for (int q = 0; q < 4; ++q) {
                int row = r0 + i * 16 + rg * 4 + q;
                O[(size_t)row * DOUT + col] = acc[i][j][q] + bv[j];
            }
        }
    }
}

// ---------------------------------------------------------------------------
extern "C" void kernel_launch(void* const* d_in, const int* in_sizes, int n_in,
                              void* d_out, int out_size, void* d_ws, size_t ws_size,
                              hipStream_t stream) {
    const float* input  = (const float*)d_in[0];  // [B,S,DIN]
    const float* meta   = (const float*)d_in[1];  // [B,P]
    const float* left   = (const float*)d_in[2];  // [P,DIN]
    const float* right  = (const float*)d_in[3];  // [P,DOUT]
    const float* bias_w = (const float*)d_in[4];  // [P,DOUT]
    const float* bias_b = (const float*)d_in[5];  // [DOUT]
    float* out = (float*)d_out;                   // [B,S,DOUT]

    // Workspace: Hsw 16 MB | mb 64 KB | Lb 1 MB | Rt 1 MB
    char* ws  = (char*)d_ws;
    char* Hsw = ws;
    float* mb = (float*)(ws + 16777216);
    short* Lb = (short*)(ws + 16777216 + 65536);
    short* Rt = (short*)(ws + 16777216 + 65536 + 1048576);

    cvt_left  <<<256, 256, 0, stream>>>(left, Lb);
    transposeR<<<dim3(DOUT / 64, P_ / 64), 256, 0, stream>>>(right, Rt);
    meta_bias <<<64, 256, 0, stream>>>(meta, bias_w, bias_b, mb);

    gemm1<<<dim3(M_ / 64), 256, 0, stream>>>(input, Lb, meta, Hsw);
    gemm2<<<dim3(M_ / 64, DOUT / 256), 256, 0, stream>>>(Hsw, Rt, mb, out);
}

// Round 7
// 572.839 us; speedup vs baseline: 1.0422x; 1.0422x over previous
//
#include <hip/hip_runtime.h>
#include <hip/hip_bf16.h>
#include <stdint.h>

#define B_    8
#define S_    4096
#define DIN   2048
#define DOUT  2048
#define P_    256
#define M_    (B_ * S_)   // 32768

typedef __attribute__((ext_vector_type(4))) float f32x4;
typedef __attribute__((ext_vector_type(8))) short bf16x8;

static __device__ __forceinline__ short f2bs(float x) {
    __hip_bfloat16 h = __float2bfloat16(x);
    return *reinterpret_cast<short*>(&h);
}

// XOR swizzle for 64x64 bf16 tiles (row stride 128 B)
#define SWZ(row, byteoff) ((byteoff) ^ (((row) & 7) << 4))

// ---------------------------------------------------------------------------
// Prep 1: left [P][DIN] fp32 -> bf16 fragment-ordered Lf.
// Fragment (p, kt, kk, rg) = left[p][kt*64+kk*32+rg*8 .. +8] stored at
// idx16 = (((p>>4)*32 + kt)*2 + kk)*4 + rg)*16 + (p&15)   (16 B units).
// A wave-load of (lm=0..15, rg=0..3) is 1024 contiguous bytes.
// ---------------------------------------------------------------------------
__global__ __launch_bounds__(256)
void prep_Lfrag(const float* __restrict__ L, short* __restrict__ Lf) {
    int g = blockIdx.x * 256 + threadIdx.x;   // 65536 fragments
    int p  = g >> 8;                          // 0..255
    int c8 = g & 255;
    int k  = c8 * 8;
    int kt = k >> 6, kk = (k >> 5) & 1, rg = (k >> 3) & 3;
    const float* src = L + (size_t)p * DIN + k;
    float4 v0 = *reinterpret_cast<const float4*>(src);
    float4 v1 = *reinterpret_cast<const float4*>(src + 4);
    bf16x8 o;
    o[0]=f2bs(v0.x); o[1]=f2bs(v0.y); o[2]=f2bs(v0.z); o[3]=f2bs(v0.w);
    o[4]=f2bs(v1.x); o[5]=f2bs(v1.y); o[6]=f2bs(v1.z); o[7]=f2bs(v1.w);
    size_t idx16 = ((((size_t)(p >> 4) * 32 + kt) * 2 + kk) * 4 + rg) * 16 + (p & 15);
    reinterpret_cast<bf16x8*>(Lf)[idx16] = o;
}

// ---------------------------------------------------------------------------
// Prep 2: right [P][DOUT] fp32 -> transposed bf16 fragment-ordered Rf.
// Fragment (n, kt, kk, rg) = right[kt*64+kk*32+rg*8 .. +8][n] at
// idx16 = ((((n>>4)*4 + kt)*2 + kk)*4 + rg)*16 + (n&15).
// ---------------------------------------------------------------------------
__global__ __launch_bounds__(256)
void prep_Rfrag(const float* __restrict__ R, short* __restrict__ Rf) {
    __shared__ float T[64][65];
    const int n0 = blockIdx.x * 64;   // DOUT dim
    const int p0 = blockIdx.y * 64;   // P dim
    const int tid = threadIdx.x;
    #pragma unroll
    for (int e = 0; e < 16; ++e) {
        int idx = tid + e * 256;
        int r = idx >> 6, c = idx & 63;       // r: p-local, c: n-local
        T[r][c] = R[(size_t)(p0 + r) * DOUT + n0 + c];
    }
    __syncthreads();
    #pragma unroll
    for (int e = 0; e < 2; ++e) {
        int q  = tid + e * 256;               // 512 fragments/tile
        int nl = q >> 3;                      // 0..63
        int pg = q & 7;                       // p-group of 8
        bf16x8 o;
        #pragma unroll
        for (int u = 0; u < 8; ++u) o[u] = f2bs(T[pg * 8 + u][nl]);
        int n = n0 + nl;
        int pglob = p0 + pg * 8;
        int kt = pglob >> 6, kk = (pglob >> 5) & 1, rg = (pglob >> 3) & 3;
        size_t idx16 = ((((size_t)(n >> 4) * 4 + kt) * 2 + kk) * 4 + rg) * 16 + (n & 15);
        reinterpret_cast<bf16x8*>(Rf)[idx16] = o;
    }
}

// ---------------------------------------------------------------------------
// Prep 3: mb[b,k] = meta[b,:] @ bias_w[:,k] + bias_b[k].  64 blocks.
// ---------------------------------------------------------------------------
__global__ __launch_bounds__(256)
void meta_bias(const float* __restrict__ meta,
               const float* __restrict__ bias_w,
               const float* __restrict__ bias_b,
               float* __restrict__ mb) {
    int b = blockIdx.x >> 3;
    int k = (blockIdx.x & 7) * 256 + threadIdx.x;
    const float* mrow = meta + b * P_;
    float acc = bias_b[k];
    #pragma unroll 8
    for (int p = 0; p < P_; ++p)
        acc = fmaf(mrow[p], bias_w[(size_t)p * DOUT + k], acc);
    mb[(size_t)b * DOUT + k] = acc;
}

// ---------------------------------------------------------------------------
// FUSED kernel: per 64-row block,
//   phase 1: Htile[64][256] = bf16( (X @ left^T) * meta )  (kept in LDS)
//   phase 2: out[64][2048]  = Htile @ right + mb
// 256 threads = 4 waves; wave w -> cols w*64.. (phase 1) / per-nb w*64.. (phase 2).
// A (X fp32): reg prefetch (T14) + cvt + ds_write, double-buffered 2x8 KB.
// B operands: coalesced fragment-order loads from L2 (no LDS, no reuse in block).
// LDS 48 KB -> 2 blocks/CU.  Grid 512.
// ---------------------------------------------------------------------------
__global__ __launch_bounds__(256, 2)
void fused(const float* __restrict__ X, const short* __restrict__ Lf,
           const short* __restrict__ Rf, const float* __restrict__ meta,
           const float* __restrict__ mb, float* __restrict__ O) {
    __shared__ short As[2][64 * 64];   // 16 KB
    __shared__ short Ht[4][64 * 64];   // 32 KB: sub-image t covers p in [t*64, t*64+64)

    const int tid  = threadIdx.x;
    const int lane = tid & 63;
    const int w    = tid >> 6;
    const int lm   = lane & 15;
    const int rg   = lane >> 4;
    const int mblk = blockIdx.x;       // 0..511
    const int r0   = mblk * 64;
    const int bidx = mblk >> 6;

    const bf16x8* Lf8 = reinterpret_cast<const bf16x8*>(Lf);
    const bf16x8* Rf8 = reinterpret_cast<const bf16x8*>(Rf);

    // ---------------- phase 1 ----------------
    const int row_s = tid >> 2;        // 0..63
    const int kq    = (tid & 3) * 16;  // float offset within 64-float k-tile
    const float* xbase = X + (size_t)(r0 + row_s) * DIN + kq;
    const int wsw0 = SWZ(row_s, row_s * 128 + kq * 2);
    const int wsw1 = SWZ(row_s, row_s * 128 + kq * 2 + 16);

    f32x4 acc[4][4] = {};
    float4 xr0, xr1, xr2, xr3;
    {
        const float4* s = reinterpret_cast<const float4*>(xbase);
        xr0 = s[0]; xr1 = s[1]; xr2 = s[2]; xr3 = s[3];
    }

    for (int kt = 0; kt < 32; ++kt) {
        char* asb = (char*)As[kt & 1];
        bf16x8 o0, o1;
        o0[0]=f2bs(xr0.x); o0[1]=f2bs(xr0.y); o0[2]=f2bs(xr0.z); o0[3]=f2bs(xr0.w);
        o0[4]=f2bs(xr1.x); o0[5]=f2bs(xr1.y); o0[6]=f2bs(xr1.z); o0[7]=f2bs(xr1.w);
        o1[0]=f2bs(xr2.x); o1[1]=f2bs(xr2.y); o1[2]=f2bs(xr2.z); o1[3]=f2bs(xr2.w);
        o1[4]=f2bs(xr3.x); o1[5]=f2bs(xr3.y); o1[6]=f2bs(xr3.z); o1[7]=f2bs(xr3.w);
        *reinterpret_cast<bf16x8*>(asb + wsw0) = o0;
        *reinterpret_cast<bf16x8*>(asb + wsw1) = o1;
        __syncthreads();

        if (kt < 31) {   // issue next k-tile's X loads now (T14)
            const float4* s = reinterpret_cast<const float4*>(xbase + (kt + 1) * 64);
            xr0 = s[0]; xr1 = s[1]; xr2 = s[2]; xr3 = s[3];
        }

        // B fragments: coalesced (64 lanes = 1024 contiguous bytes per (j,kk))
        bf16x8 bfr[4][2];
        #pragma unroll
        for (int j = 0; j < 4; ++j)
            #pragma unroll
            for (int kk = 0; kk < 2; ++kk)
                bfr[j][kk] = Lf8[((((size_t)(w * 4 + j) * 32 + kt) * 2 + kk) * 4) * 16
                                 + rg * 16 + lm];

        #pragma unroll
        for (int kk = 0; kk < 2; ++kk) {
            bf16x8 af[4];
            #pragma unroll
            for (int i = 0; i < 4; ++i) {
                int m = i * 16 + lm;
                af[i] = *reinterpret_cast<const bf16x8*>(
                    asb + SWZ(m, m * 128 + (kk * 32 + rg * 8) * 2));
            }
            #pragma unroll
            for (int i = 0; i < 4; ++i)
                #pragma unroll
                for (int j = 0; j < 4; ++j)
                    acc[i][j] = __builtin_amdgcn_mfma_f32_16x16x32_bf16(
                        af[i], bfr[j][kk], acc[i][j], 0, 0, 0);
        }
        // no trailing barrier: double buffer
    }

    // phase-1 epilogue: *meta, write swizzled Htile sub-image w (LDS only)
    {
        const float* mrow = meta + bidx * P_;
        char* hb = (char*)Ht[w];
        float mv[4];
        #pragma unroll
        for (int j = 0; j < 4; ++j) mv[j] = mrow[w * 64 + j * 16 + lm];
        #pragma unroll
        for (int i = 0; i < 4; ++i) {
            #pragma unroll
            for (int j = 0; j < 4; ++j) {
                int kk2 = j * 16 + lm;             // p-local within sub-image
                #pragma unroll
                for (int q = 0; q < 4; ++q) {
                    int r = i * 16 + rg * 4 + q;   // row-local 0..63
                    *reinterpret_cast<short*>(hb + SWZ(r, r * 128 + kk2 * 2)) =
                        f2bs(acc[i][j][q] * mv[j]);
                }
            }
        }
    }
    __syncthreads();   // Htile complete; phase 2 is read-only on LDS

    // ---------------- phase 2 ----------------
    const float* mbr = mb + (size_t)bidx * DOUT;
    for (int nb = 0; nb < 8; ++nb) {
        f32x4 acc2[4][4] = {};
        #pragma unroll
        for (int kt2 = 0; kt2 < 4; ++kt2) {
            bf16x8 bfr2[4][2];
            #pragma unroll
            for (int j = 0; j < 4; ++j)
                #pragma unroll
                for (int kk = 0; kk < 2; ++kk)
                    bfr2[j][kk] = Rf8[((((size_t)(nb * 16 + w * 4 + j) * 4 + kt2) * 2 + kk) * 4) * 16
                                      + rg * 16 + lm];
            const char* hsb = (const char*)Ht[kt2];
            #pragma unroll
            for (int kk = 0; kk < 2; ++kk) {
                bf16x8 af[4];
                #pragma unroll
                for (int i = 0; i < 4; ++i) {
                    int m = i * 16 + lm;
                    af[i] = *reinterpret_cast<const bf16x8*>(
                        hsb + SWZ(m, m * 128 + (kk * 32 + rg * 8) * 2));
                }
                #pragma unroll
                for (int i = 0; i < 4; ++i)
                    #pragma unroll
                    for (int j = 0; j < 4; ++j)
                        acc2[i][j] = __builtin_amdgcn_mfma_f32_16x16x32_bf16(
                            af[i], bfr2[j][kk], acc2[i][j], 0, 0, 0);
            }
        }
        // store this 256-col chunk
        #pragma unroll
        for (int j = 0; j < 4; ++j) {
            int col = nb * 256 + w * 64 + j * 16 + lm;
            float bv = mbr[col];
            #pragma unroll
            for (int i = 0; i < 4; ++i) {
                #pragma unroll
                for (int q = 0; q < 4; ++q) {
                    int row = r0 + i * 16 + rg * 4 + q;
                    O[(size_t)row * DOUT + col] = acc2[i][j][q] + bv;
                }
            }
        }
    }
}

// ---------------------------------------------------------------------------
extern "C" void kernel_launch(void* const* d_in, const int* in_sizes, int n_in,
                              void* d_out, int out_size, void* d_ws, size_t ws_size,
                              hipStream_t stream) {
    const float* input  = (const float*)d_in[0];  // [B,S,DIN]
    const float* meta   = (const float*)d_in[1];  // [B,P]
    const float* left   = (const float*)d_in[2];  // [P,DIN]
    const float* right  = (const float*)d_in[3];  // [P,DOUT]
    const float* bias_w = (const float*)d_in[4];  // [P,DOUT]
    const float* bias_b = (const float*)d_in[5];  // [DOUT]
    float* out = (float*)d_out;                   // [B,S,DOUT]

    // Workspace: mb 64 KB | Lf 1 MB | Rf 1 MB
    char* ws  = (char*)d_ws;
    float* mb = (float*)ws;
    short* Lf = (short*)(ws + 65536);
    short* Rf = (short*)(ws + 65536 + 1048576);

    prep_Lfrag<<<256, 256, 0, stream>>>(left, Lf);
    prep_Rfrag<<<dim3(DOUT / 64, P_ / 64), 256, 0, stream>>>(right, Rf);
    meta_bias <<<64, 256, 0, stream>>>(meta, bias_w, bias_b, mb);

    fused<<<dim3(M_ / 64), 256, 0, stream>>>(input, Lf, Rf, meta, mb, out);
}